// Round 1
// baseline (171.623 us; speedup 1.0000x reference)
//
#include <hip/hip_runtime.h>
#include <hip/hip_bf16.h>

// Problem constants
#define B_  256
#define C_  256
#define CH_ 128
#define N_  196            // H*W = 14*14
#define NF4 49             // 196 floats = 49 float4 per (b,c) row
#define EPS 1e-5f

// ---------------------------------------------------------------------------
// K1: Ysum[b,c] = sum_n y[b,c,n].  One 64-lane wave per row of 196 floats.
// Lanes 0..48 each load one float4 (784 B contiguous per wave), then a
// width-64 shuffle butterfly reduces to lane 0.
// ---------------------------------------------------------------------------
__global__ __launch_bounds__(256) void k_ysum(const float* __restrict__ y,
                                              float* __restrict__ ysum) {
    int wave = blockIdx.x * 4 + (threadIdx.x >> 6);   // global row id (< 65536)
    int lane = threadIdx.x & 63;
    const float4* row = (const float4*)(y + (size_t)wave * N_);
    float s = 0.f;
    if (lane < NF4) {
        float4 v = row[lane];
        s = (v.x + v.y) + (v.z + v.w);
    }
    #pragma unroll
    for (int off = 32; off > 0; off >>= 1)
        s += __shfl_down(s, off, 64);
    if (lane == 0) ysum[wave] = s;
}

// ---------------------------------------------------------------------------
// K2: WzvT[c][o] = sum_k Wz[o,k] * Wv[k,c]   (Wz: [C,CH], Wv: [CH,C])
// Block per c (grid 256), thread per o (256 threads). Wv column c staged in
// LDS; Wz rows are L2-resident (128 KB total). Writes are fully coalesced.
// ---------------------------------------------------------------------------
__global__ __launch_bounds__(256) void k_wzvt(const float* __restrict__ Wz,
                                              const float* __restrict__ Wv,
                                              float* __restrict__ WzvT) {
    __shared__ float sWv[CH_];
    int c = blockIdx.x;
    int o = threadIdx.x;
    if (o < CH_) sWv[o] = Wv[o * C_ + c];
    __syncthreads();
    const float4* wzrow = (const float4*)(Wz + o * CH_);
    float acc = 0.f;
    #pragma unroll
    for (int k4 = 0; k4 < CH_ / 4; k4++) {
        float4 w = wzrow[k4];
        acc += w.x * sWv[4 * k4 + 0];
        acc += w.y * sWv[4 * k4 + 1];
        acc += w.z * sWv[4 * k4 + 2];
        acc += w.w * sWv[4 * k4 + 3];
    }
    WzvT[c * C_ + o] = acc;
}

// ---------------------------------------------------------------------------
// K3: Zs[b,o] = (Ysum[b,:] . WzvT[:,o] - bn_mean[o]) * bn_w[o]*rsqrt(var+eps)
//              + bn_bias[o]
// Block per b (grid 256), thread per o. Ysum[b,:] broadcast from LDS;
// WzvT reads coalesced across o and L2-hot (256 KB reused by all blocks).
// ---------------------------------------------------------------------------
__global__ __launch_bounds__(256) void k_z2(const float* __restrict__ ysum,
                                            const float* __restrict__ WzvT,
                                            const float* __restrict__ bnw,
                                            const float* __restrict__ bnb,
                                            const float* __restrict__ bnm,
                                            const float* __restrict__ bnv,
                                            float* __restrict__ Zs) {
    __shared__ float sY[C_];
    int b = blockIdx.x;
    int o = threadIdx.x;
    sY[o] = ysum[b * C_ + o];
    __syncthreads();
    float acc = 0.f;
    #pragma unroll 8
    for (int c = 0; c < C_; c++)
        acc += sY[c] * WzvT[c * C_ + o];
    float alpha = bnw[o] * rsqrtf(bnv[o] + EPS);
    Zs[b * C_ + o] = (acc - bnm[o]) * alpha + bnb[o];
}

// ---------------------------------------------------------------------------
// K4: out[b,c,n] = x[b,c,n] + Zs[b,c].  float4 per thread; row = idx/49
// (compiler emits a magic-multiply). Zs reads are 49-thread broadcasts,
// served from L1/L2.
// ---------------------------------------------------------------------------
__global__ __launch_bounds__(256) void k_out(const float* __restrict__ x,
                                             const float* __restrict__ Zs,
                                             float* __restrict__ out) {
    int idx = blockIdx.x * blockDim.x + threadIdx.x;  // float4 index
    int row = idx / NF4;
    float z = Zs[row];
    float4 v = ((const float4*)x)[idx];
    v.x += z; v.y += z; v.z += z; v.w += z;
    ((float4*)out)[idx] = v;
}

extern "C" void kernel_launch(void* const* d_in, const int* in_sizes, int n_in,
                              void* d_out, int out_size, void* d_ws, size_t ws_size,
                              hipStream_t stream) {
    const float* x   = (const float*)d_in[0];
    const float* y   = (const float*)d_in[1];
    // d_in[2] = Wq, d_in[3] = Wk : dead code (softmax over singleton axis == 1)
    const float* Wv  = (const float*)d_in[4];
    const float* Wz  = (const float*)d_in[5];
    const float* bnw = (const float*)d_in[6];
    const float* bnb = (const float*)d_in[7];
    const float* bnm = (const float*)d_in[8];
    const float* bnv = (const float*)d_in[9];
    float* out = (float*)d_out;

    float* ysum = (float*)d_ws;                 // 65536 floats
    float* WzvT = ysum + B_ * C_;               // 65536 floats
    float* Zs   = WzvT + C_ * C_;               // 65536 floats

    // K1: 65536 rows, 4 waves (rows) per 256-thread block
    k_ysum<<<(B_ * C_) / 4, 256, 0, stream>>>(y, ysum);
    // K2: fused weight product (independent of K1, tiny)
    k_wzvt<<<C_, 256, 0, stream>>>(Wz, Wv, WzvT);
    // K3: per-batch channel mix + BN affine fold
    k_z2<<<B_, 256, 0, stream>>>(ysum, WzvT, bnw, bnb, bnm, bnv, Zs);
    // K4: residual broadcast-add epilogue. 65536*49 float4s, 256/block.
    k_out<<<(B_ * C_ * NF4) / 256, 256, 0, stream>>>(x, Zs, out);
}